// Round 1
// baseline (8161.673 us; speedup 1.0000x reference)
//
#include <hip/hip_runtime.h>
#include <stdint.h>

#define TT 128
#define BB 128
#define DD 300
#define EE 1024
#define GG 900
#define G2 3072
#define NMU 1000
#define ASP 500

#define OUT_SLOG 131072
#define OUT_ACT  163840
#define OUT_LOGP 196608

// ---------------- threefry2x32 (JAX, 20 rounds) ----------------
__host__ __device__ static inline uint32_t rotl32(uint32_t x, int r){
  return (x << r) | (x >> (32 - r));
}

__host__ __device__ static inline void tf2x32(uint32_t k0, uint32_t k1,
                                              uint32_t x0, uint32_t x1,
                                              uint32_t* o0, uint32_t* o1){
  uint32_t ks2 = k0 ^ k1 ^ 0x1BD11BDAu;
#define TFR(r) { x0 += x1; x1 = rotl32(x1, r); x1 ^= x0; }
  x0 += k0; x1 += k1;
  TFR(13) TFR(15) TFR(26) TFR(6)
  x0 += k1; x1 += ks2 + 1u;
  TFR(17) TFR(29) TFR(16) TFR(24)
  x0 += ks2; x1 += k0 + 2u;
  TFR(13) TFR(15) TFR(26) TFR(6)
  x0 += k0; x1 += k1 + 3u;
  TFR(17) TFR(29) TFR(16) TFR(24)
  x0 += k1; x1 += ks2 + 4u;
  TFR(13) TFR(15) TFR(26) TFR(6)
  x0 += ks2; x1 += k0 + 5u;
#undef TFR
  *o0 = x0; *o1 = x1;
}

// partitionable random_bits: counts (0, idx), fold with XOR
__device__ static inline uint32_t rng32(uint32_t k0, uint32_t k1, uint32_t idx){
  uint32_t a, b;
  tf2x32(k0, k1, 0u, idx, &a, &b);
  return a ^ b;
}

__device__ static inline float u01(uint32_t bits){
  return __uint_as_float((bits >> 9) | 0x3f800000u) - 1.0f;
}

__device__ static inline float jgumbel(uint32_t k0, uint32_t k1, uint32_t idx){
  float u = u01(rng32(k0, k1, idx));
  float l1 = logf(u + 1e-20f);
  return -logf(-l1 + 1e-20f);
}

__device__ static inline float erfinv32(float x){   // XLA ErfInv32 (Giles)
  float w = -log1pf(-x * x);
  float p;
  if (w < 5.0f){
    w = w - 2.5f;
    p = 2.81022636e-08f;
    p = 3.43273939e-07f  + p * w;
    p = -3.5233877e-06f  + p * w;
    p = -4.39150654e-06f + p * w;
    p = 0.00021858087f   + p * w;
    p = -0.00125372503f  + p * w;
    p = -0.00417768164f  + p * w;
    p = 0.246640727f     + p * w;
    p = 1.50140941f      + p * w;
  } else {
    w = sqrtf(w) - 3.0f;
    p = -0.000200214257f;
    p = 0.000100950558f  + p * w;
    p = 0.00134934322f   + p * w;
    p = -0.00367342844f  + p * w;
    p = 0.00573950773f   + p * w;
    p = -0.0076224613f   + p * w;
    p = 0.00943887047f   + p * w;
    p = 1.00167406f      + p * w;
    p = 2.83297682f      + p * w;
  }
  return p * x;
}

__device__ static inline float jnormal(uint32_t k0, uint32_t k1, uint32_t idx){
  float u = u01(rng32(k0, k1, idx));
  const float lo = -0.99999994f;              // nextafter(-1, 0) in f32
  float v = u * 2.0f + lo;                    // (hi - lo) rounds to 2.0f
  v = fmaxf(lo, v);
  return 1.41421356237f * erfinv32(v);
}

__device__ static inline float jsigmoid(float x){
  return 1.0f / (1.0f + expf(-x));
}

// ---------------- GEMM1: gi_all[r=(t*BB+b)][900] = x@Wih_c^T + bih ----------------
__global__ __launch_bounds__(256) void k_gemm_gi(
    const float* __restrict__ X, const float* __restrict__ W,
    const float* __restrict__ bias, float* __restrict__ C)
{
  __shared__ float As[16][64];
  __shared__ float Bs[16][68];
  const int tid = threadIdx.x;
  const int rbase = blockIdx.y * 64;
  const int cbase = blockIdx.x * 64;
  const int tx = tid & 15, ty = tid >> 4;
  const int lrow = tid >> 2, lq = tid & 3;

  const int rg = rbase + lrow;
  const float* xrow = X + ((long)(rg & 127) * TT + (rg >> 7)) * DD;
  const int wj = cbase + lrow;

  float4 c0 = {0,0,0,0}, c1 = {0,0,0,0}, c2 = {0,0,0,0}, c3 = {0,0,0,0};

  for (int k0 = 0; k0 < DD; k0 += 16){
    int k = k0 + lq * 4;
    float4 va = {0,0,0,0};
    if (k < DD) va = *(const float4*)(xrow + k);
    As[lq*4+0][lrow] = va.x; As[lq*4+1][lrow] = va.y;
    As[lq*4+2][lrow] = va.z; As[lq*4+3][lrow] = va.w;
    float4 vb = {0,0,0,0};
    if (k < DD && wj < GG) vb = *(const float4*)(W + (long)wj * DD + k);
    Bs[lq*4+0][lrow] = vb.x; Bs[lq*4+1][lrow] = vb.y;
    Bs[lq*4+2][lrow] = vb.z; Bs[lq*4+3][lrow] = vb.w;
    __syncthreads();
#pragma unroll
    for (int kk = 0; kk < 16; ++kk){
      const float4 a = *(const float4*)&As[kk][ty * 4];
      const float4 b = *(const float4*)&Bs[kk][tx * 4];
      c0.x += a.x*b.x; c0.y += a.x*b.y; c0.z += a.x*b.z; c0.w += a.x*b.w;
      c1.x += a.y*b.x; c1.y += a.y*b.y; c1.z += a.y*b.z; c1.w += a.y*b.w;
      c2.x += a.z*b.x; c2.y += a.z*b.y; c2.z += a.z*b.z; c2.w += a.z*b.w;
      c3.x += a.w*b.x; c3.y += a.w*b.y; c3.z += a.w*b.z; c3.w += a.w*b.w;
    }
    __syncthreads();
  }
  const int ci = cbase + tx * 4;
  const int r0 = rbase + ty * 4;
  float bv[4];
#pragma unroll
  for (int j = 0; j < 4; ++j) bv[j] = (ci + j < GG) ? bias[ci + j] : 0.0f;
  float4 rows[4] = {c0, c1, c2, c3};
#pragma unroll
  for (int i = 0; i < 4; ++i){
    float vals[4] = {rows[i].x + bv[0], rows[i].y + bv[1],
                     rows[i].z + bv[2], rows[i].w + bv[3]};
    float* crow = C + (long)(r0 + i) * GG;
    if (ci + 3 < GG){
      float4 st = {vals[0], vals[1], vals[2], vals[3]};
      *(float4*)(crow + ci) = st;
    } else {
#pragma unroll
      for (int j = 0; j < 4; ++j) if (ci + j < GG) crow[ci + j] = vals[j];
    }
  }
}

// ---------------- GEMM-mu: mu_all[r][1000] = relu([img|hx])@Wmu^T + bmu ----------------
__global__ __launch_bounds__(256) void k_gemm_mu(
    const float* __restrict__ X, const float* __restrict__ HX,
    const float* __restrict__ W, const float* __restrict__ bias,
    float* __restrict__ C)
{
  __shared__ float As[16][64];
  __shared__ float Bs[16][68];
  const int tid = threadIdx.x;
  const int rbase = blockIdx.y * 64;
  const int cbase = blockIdx.x * 64;
  const int tx = tid & 15, ty = tid >> 4;
  const int lrow = tid >> 2, lq = tid & 3;

  const int rg = rbase + lrow;
  const float* xrow = X + ((long)(rg & 127) * TT + (rg >> 7)) * DD;
  const float* hrow = HX + (long)rg * DD;
  const int wj = cbase + lrow;

  float4 c0 = {0,0,0,0}, c1 = {0,0,0,0}, c2 = {0,0,0,0}, c3 = {0,0,0,0};

  for (int k0 = 0; k0 < 600; k0 += 16){
    int k = k0 + lq * 4;
    float4 va = {0,0,0,0};
    if (k < 300)      va = *(const float4*)(xrow + k);
    else if (k < 600) va = *(const float4*)(hrow + (k - 300));
    va.x = fmaxf(va.x, 0.0f); va.y = fmaxf(va.y, 0.0f);
    va.z = fmaxf(va.z, 0.0f); va.w = fmaxf(va.w, 0.0f);
    As[lq*4+0][lrow] = va.x; As[lq*4+1][lrow] = va.y;
    As[lq*4+2][lrow] = va.z; As[lq*4+3][lrow] = va.w;
    float4 vb = {0,0,0,0};
    if (k < 600 && wj < NMU) vb = *(const float4*)(W + (long)wj * 600 + k);
    Bs[lq*4+0][lrow] = vb.x; Bs[lq*4+1][lrow] = vb.y;
    Bs[lq*4+2][lrow] = vb.z; Bs[lq*4+3][lrow] = vb.w;
    __syncthreads();
#pragma unroll
    for (int kk = 0; kk < 16; ++kk){
      const float4 a = *(const float4*)&As[kk][ty * 4];
      const float4 b = *(const float4*)&Bs[kk][tx * 4];
      c0.x += a.x*b.x; c0.y += a.x*b.y; c0.z += a.x*b.z; c0.w += a.x*b.w;
      c1.x += a.y*b.x; c1.y += a.y*b.y; c1.z += a.y*b.z; c1.w += a.y*b.w;
      c2.x += a.z*b.x; c2.y += a.z*b.y; c2.z += a.z*b.z; c2.w += a.z*b.w;
      c3.x += a.w*b.x; c3.y += a.w*b.y; c3.z += a.w*b.z; c3.w += a.w*b.w;
    }
    __syncthreads();
  }
  const int ci = cbase + tx * 4;
  const int r0 = rbase + ty * 4;
  float bv[4];
#pragma unroll
  for (int j = 0; j < 4; ++j) bv[j] = (ci + j < NMU) ? bias[ci + j] : 0.0f;
  float4 rows[4] = {c0, c1, c2, c3};
#pragma unroll
  for (int i = 0; i < 4; ++i){
    float vals[4] = {rows[i].x + bv[0], rows[i].y + bv[1],
                     rows[i].z + bv[2], rows[i].w + bv[3]};
    float* crow = C + (long)(r0 + i) * NMU;
    if (ci + 3 < NMU){
      float4 st = {vals[0], vals[1], vals[2], vals[3]};
      *(float4*)(crow + ci) = st;
    } else {
#pragma unroll
      for (int j = 0; j < 4; ++j) if (ci + j < NMU) crow[ci + j] = vals[j];
    }
  }
}

// ---------------- lv (pre-softplus): lv_all[r][2] = relu(cat)@Wlv^T + blv ----------------
__global__ __launch_bounds__(256) void k_lv(
    const float* __restrict__ X, const float* __restrict__ HX,
    const float* __restrict__ Wlv, const float* __restrict__ blv,
    float* __restrict__ LV)
{
  const int r = blockIdx.x * 256 + threadIdx.x;   // 16384
  const float* xr = X + ((long)(r & 127) * TT + (r >> 7)) * DD;
  const float* hr = HX + (long)r * DD;
  float a0 = 0.0f, a1 = 0.0f;
  for (int k = 0; k < DD; ++k){
    float v = fmaxf(xr[k], 0.0f);
    a0 += v * Wlv[k]; a1 += v * Wlv[600 + k];
  }
  for (int k = 0; k < DD; ++k){
    float v = fmaxf(hr[k], 0.0f);
    a0 += v * Wlv[300 + k]; a1 += v * Wlv[900 + k];
  }
  LV[(long)r * 2 + 0] = a0 + blv[0];
  LV[(long)r * 2 + 1] = a1 + blv[1];
}

// ---------------- stage-1 recurrence step: hx GEMM (K=300) + GRU gates ----------------
__global__ __launch_bounds__(256) void k_hx_step(
    const int t, const float* __restrict__ hp, const float* __restrict__ Whh,
    const float* __restrict__ bhh, const float* __restrict__ gi_all,
    float* __restrict__ hx_out)
{
  __shared__ float Hs[32][66];   // [k][64 rows + pad]
  __shared__ float Ws[32][32];   // [k][jx*4 + gate]
  const int tid = threadIdx.x;
  const int jx = tid & 7, bq = tid >> 3;
  const int jjBase = blockIdx.x * 8;
  const int bBase = blockIdx.y * 64;
  float aR[2] = {0,0}, aZ[2] = {0,0}, aN[2] = {0,0};

  for (int k0 = 0; k0 < DD; k0 += 32){
    for (int e = tid; e < 512; e += 256){
      int rr = e >> 3, kq = e & 7;
      int k = k0 + kq * 4;
      float4 v = {0,0,0,0};
      if (k < DD) v = *(const float4*)(hp + (long)(bBase + rr) * DD + k);
      Hs[kq*4+0][rr] = v.x; Hs[kq*4+1][rr] = v.y;
      Hs[kq*4+2][rr] = v.z; Hs[kq*4+3][rr] = v.w;
    }
    if (tid < 192){
      int wr = tid >> 3, kq = tid & 7;
      int g = wr >> 3, jw = wr & 7;
      int jjw = jjBase + jw;
      int k = k0 + kq * 4;
      float4 v = {0,0,0,0};
      if (k < DD && jjw < DD) v = *(const float4*)(Whh + ((long)g * DD + jjw) * DD + k);
      Ws[kq*4+0][jw*4 + g] = v.x; Ws[kq*4+1][jw*4 + g] = v.y;
      Ws[kq*4+2][jw*4 + g] = v.z; Ws[kq*4+3][jw*4 + g] = v.w;
    }
    __syncthreads();
#pragma unroll 8
    for (int kk = 0; kk < 32; ++kk){
      const float2 hv = *(const float2*)&Hs[kk][bq * 2];
      const float4 wv = *(const float4*)&Ws[kk][jx * 4];
      aR[0] += hv.x * wv.x; aZ[0] += hv.x * wv.y; aN[0] += hv.x * wv.z;
      aR[1] += hv.y * wv.x; aZ[1] += hv.y * wv.y; aN[1] += hv.y * wv.z;
    }
    __syncthreads();
  }
  const int jj = jjBase + jx;
  if (jj < DD){
#pragma unroll
    for (int i = 0; i < 2; ++i){
      const int b = bBase + bq * 2 + i;
      const float* gi = gi_all + ((long)t * BB + b) * GG;
      float ghr = aR[i] + bhh[jj];
      float ghz = aZ[i] + bhh[DD + jj];
      float ghn = aN[i] + bhh[2*DD + jj];
      float rr = jsigmoid(gi[jj] + ghr);
      float zz = jsigmoid(gi[DD + jj] + ghz);
      float nn = tanhf(gi[2*DD + jj] + rr * ghn);
      float hv = hp[(long)b * DD + jj];
      hx_out[(long)b * DD + jj] = (1.0f - zz) * nn + zz * hv;
    }
  }
}

// ---------------- sampling: softmax + gumbel-max + normal + texts ----------------
__global__ __launch_bounds__(256) void k_sample(
    const float* __restrict__ X, const float* __restrict__ mu_all,
    const float* __restrict__ lv_all, float* __restrict__ texts,
    float* __restrict__ out,
    const uint32_t k0a, const uint32_t k0b, const uint32_t k1a, const uint32_t k1b,
    const uint32_t k2a, const uint32_t k2b, const uint32_t k3a, const uint32_t k3b)
{
  const int r = blockIdx.x;            // t*128 + b
  const int t = r >> 7, b = r & 127;
  const int tid = threadIdx.x;
  const int h = tid >> 7, lane = tid & 127;
  __shared__ float redf[256];
  __shared__ int   redi[256];
  __shared__ float yw[2], lyw[2], att_s[2];

  const uint32_t rowbase = (uint32_t)((t * 256 + b * 2 + h) * 500);
  float zv[4], ev[4];
  float lmax = -3.0e38f;
#pragma unroll
  for (int s = 0; s < 4; ++s){
    const int a = lane + s * 128;
    float z = -3.0e38f;
    if (a < ASP){
      float g = jgumbel(k0a, k0b, rowbase + (uint32_t)a);
      float m = mu_all[(long)r * NMU + h * ASP + a];
      z = (m + g) / 0.8f;
    }
    zv[s] = z;
    lmax = fmaxf(lmax, z);
  }
  redf[tid] = lmax;
  __syncthreads();
  for (int off = 64; off > 0; off >>= 1){
    if (lane < off) redf[tid] = fmaxf(redf[tid], redf[tid + off]);
    __syncthreads();
  }
  const float mx = redf[h << 7];
  __syncthreads();
  float lsum = 0.0f;
#pragma unroll
  for (int s = 0; s < 4; ++s){
    const int a = lane + s * 128;
    float e = 0.0f;
    if (a < ASP) e = expf(zv[s] - mx);
    ev[s] = e;
    lsum += e;
  }
  redf[tid] = lsum;
  __syncthreads();
  for (int off = 64; off > 0; off >>= 1){
    if (lane < off) redf[tid] += redf[tid + off];
    __syncthreads();
  }
  const float S = redf[h << 7];
  __syncthreads();
  float bestv = -3.0e38f;
  int besti = 0x7fffffff;
#pragma unroll
  for (int s = 0; s < 4; ++s){
    const int a = lane + s * 128;
    if (a < ASP){
      float y = ev[s] / S;
      float ly = logf(y);
      float gc = jgumbel(k1a, k1b, rowbase + (uint32_t)a);
      float val = ly + gc;
      if (val > bestv){ bestv = val; besti = a; }
    }
  }
  redf[tid] = bestv; redi[tid] = besti;
  __syncthreads();
  for (int off = 64; off > 0; off >>= 1){
    if (lane < off){
      float v2 = redf[tid + off]; int i2 = redi[tid + off];
      if (v2 > redf[tid] || (v2 == redf[tid] && i2 < redi[tid])){
        redf[tid] = v2; redi[tid] = i2;
      }
    }
    __syncthreads();
  }
  const int ind = redi[h << 7];
#pragma unroll
  for (int s = 0; s < 4; ++s){
    const int a = lane + s * 128;
    if (a == ind){
      float y = ev[s] / S;
      yw[h] = y;
      lyw[h] = logf(y);
    }
  }
  __syncthreads();
  if (lane == 0){
    const float yv = yw[h];
    const float ly = lyw[h];
    const float yh = (1.0f - yv) + yv;                 // straight-through value
    const float act = ((float)ind * yh) / 500.0f;
    const float lvr = lv_all[(long)r * 2 + h];
    const float lv = fmaxf(lvr, 0.0f) + log1pf(expf(-fabsf(lvr)));  // softplus
    const float sd = expf(0.5f * lv);
    const uint32_t ei = (uint32_t)(r * 2 + h);
    const float e1 = jnormal(k2a, k2b, ei);
    const float e2 = jnormal(k3a, k3b, ei);
    const float s1 = act + sd * e1;
    const float s2 = act + sd * e2;
    const float dd = (s2 - act) / sd;
    const float lp = -0.5f * (dd * dd) - logf(sd) - 0.9189385332046727f;
    const float attv = 20.0f * jsigmoid(s1);
    out[OUT_SLOG + (long)b * 256 + t * 2 + h]  = ly;
    out[OUT_ACT  + (long)b * 256 + h * 128 + t] = act;
    out[OUT_LOGP + (long)b * 256 + h * 128 + t] = lp;
    att_s[h] = attv;
  }
  __syncthreads();
  const float* xr = X + ((long)b * TT + t) * DD;
  float* tr = texts + (long)r * DD;
  for (int j = tid; j < DD; j += 256){
    tr[j] = xr[j] * att_s[j / 150];
  }
}

// ---------------- stage-2 GEMM (split-K=4): gh = h2@Whh_r^T, gi = texts_t@Wih_r^T ----------------
__global__ __launch_bounds__(256) void k_gemm2(
    const int t, const float* __restrict__ H2, const float* __restrict__ TX,
    const float* __restrict__ Whh, const float* __restrict__ Wih,
    float* __restrict__ parts)
{
  __shared__ float As[32][34];
  __shared__ float Bs[32][68];
  const int tid = threadIdx.x;
  const int tx = tid & 15, ty = tid >> 4;
  const int obase = blockIdx.x * 64;
  const int bbase = blockIdx.y * 32;
  const int sl = blockIdx.z;
  const int arr = tid >> 3, akq = tid & 7;
  float4 h0 = {0,0,0,0}, h1 = {0,0,0,0};
  float4 i0 = {0,0,0,0}, i1 = {0,0,0,0};

  // phase 1: hidden part, K-slice [sl*256, sl*256+256)
  for (int kc = 0; kc < 256; kc += 32){
    const int k0 = sl * 256 + kc;
    {
      float4 v = *(const float4*)(H2 + (long)(bbase + arr) * EE + k0 + akq * 4);
      As[akq*4+0][arr] = v.x; As[akq*4+1][arr] = v.y;
      As[akq*4+2][arr] = v.z; As[akq*4+3][arr] = v.w;
    }
    for (int e = tid; e < 512; e += 256){
      int orow = e >> 3, kq = e & 7;
      float4 v = *(const float4*)(Whh + (long)(obase + orow) * EE + k0 + kq * 4);
      Bs[kq*4+0][orow] = v.x; Bs[kq*4+1][orow] = v.y;
      Bs[kq*4+2][orow] = v.z; Bs[kq*4+3][orow] = v.w;
    }
    __syncthreads();
#pragma unroll 8
    for (int kk = 0; kk < 32; ++kk){
      const float2 a = *(const float2*)&As[kk][ty * 2];
      const float4 bv = *(const float4*)&Bs[kk][tx * 4];
      h0.x += a.x*bv.x; h0.y += a.x*bv.y; h0.z += a.x*bv.z; h0.w += a.x*bv.w;
      h1.x += a.y*bv.x; h1.y += a.y*bv.y; h1.z += a.y*bv.z; h1.w += a.y*bv.w;
    }
    __syncthreads();
  }
  // phase 2: input part, K-slice [sl*76, min(300, sl*76+76))
  const int ks = sl * 76;
  const int ke = (sl == 3) ? 300 : (ks + 76);
  for (int kc = ks; kc < ke; kc += 32){
    {
      int k = kc + akq * 4;
      float4 v = {0,0,0,0};
      if (k < ke) v = *(const float4*)(TX + ((long)t * BB + bbase + arr) * DD + k);
      As[akq*4+0][arr] = v.x; As[akq*4+1][arr] = v.y;
      As[akq*4+2][arr] = v.z; As[akq*4+3][arr] = v.w;
    }
    for (int e = tid; e < 512; e += 256){
      int orow = e >> 3, kq = e & 7;
      int k = kc + kq * 4;
      float4 v = {0,0,0,0};
      if (k < ke) v = *(const float4*)(Wih + (long)(obase + orow) * DD + k);
      Bs[kq*4+0][orow] = v.x; Bs[kq*4+1][orow] = v.y;
      Bs[kq*4+2][orow] = v.z; Bs[kq*4+3][orow] = v.w;
    }
    __syncthreads();
#pragma unroll 8
    for (int kk = 0; kk < 32; ++kk){
      const float2 a = *(const float2*)&As[kk][ty * 2];
      const float4 bv = *(const float4*)&Bs[kk][tx * 4];
      i0.x += a.x*bv.x; i0.y += a.x*bv.y; i0.z += a.x*bv.z; i0.w += a.x*bv.w;
      i1.x += a.y*bv.x; i1.y += a.y*bv.y; i1.z += a.y*bv.z; i1.w += a.y*bv.w;
    }
    __syncthreads();
  }
  const int b0 = bbase + ty * 2;
  const int o0 = obase + tx * 4;
  float* pH = parts + ((long)(sl * 2 + 0) * BB) * G2;
  float* pI = parts + ((long)(sl * 2 + 1) * BB) * G2;
  *(float4*)(pH + (long)b0 * G2 + o0)       = h0;
  *(float4*)(pH + (long)(b0 + 1) * G2 + o0) = h1;
  *(float4*)(pI + (long)b0 * G2 + o0)       = i0;
  *(float4*)(pI + (long)(b0 + 1) * G2 + o0) = i1;
}

// ---------------- stage-2 gates ----------------
__global__ __launch_bounds__(256) void k_gate2(
    const int t, const float* __restrict__ parts, const float* __restrict__ bih,
    const float* __restrict__ bhh, const int* __restrict__ lengths,
    float* __restrict__ h2, float* __restrict__ last)
{
  const int gid = blockIdx.x * 256 + threadIdx.x;   // 131072
  const int b = gid >> 10, e = gid & 1023;
  float ghr = bhh[e], ghz = bhh[EE + e], ghn = bhh[2*EE + e];
  float gir = bih[e], giz = bih[EE + e], gin = bih[2*EE + e];
#pragma unroll
  for (int s = 0; s < 4; ++s){
    const float* ph = parts + ((long)(s * 2 + 0) * BB + b) * G2;
    const float* pi = parts + ((long)(s * 2 + 1) * BB + b) * G2;
    ghr += ph[e]; ghz += ph[EE + e]; ghn += ph[2*EE + e];
    gir += pi[e]; giz += pi[EE + e]; gin += pi[2*EE + e];
  }
  const float rr = jsigmoid(gir + ghr);
  const float zz = jsigmoid(giz + ghz);
  const float nn = tanhf(gin + rr * ghn);
  const float hv = h2[gid];
  const float hn = (1.0f - zz) * nn + zz * hv;
  h2[gid] = hn;
  int li = lengths[b] - 1;
  if (li < 0) li += TT;
  if (t == li) last[gid] = hn;
}

// ---------------- BatchNorm (training stats) ----------------
__global__ __launch_bounds__(256) void k_bn_stats(
    const float* __restrict__ last, float* __restrict__ mv)
{
  const int e = blockIdx.x * 256 + threadIdx.x;
  if (e >= EE) return;
  float s = 0.0f;
  for (int b = 0; b < BB; ++b) s += last[(long)b * EE + e];
  const float mean = s / 128.0f;
  float v = 0.0f;
  for (int b = 0; b < BB; ++b){ float d = last[(long)b * EE + e] - mean; v += d * d; }
  mv[e] = mean;
  mv[EE + e] = v / 128.0f;
}

__global__ __launch_bounds__(256) void k_bn_apply(
    const float* __restrict__ last, const float* __restrict__ mv,
    const float* __restrict__ gamma, const float* __restrict__ beta,
    float* __restrict__ out)
{
  const int gid = blockIdx.x * 256 + threadIdx.x;   // 131072
  const int e = gid & 1023;
  const float xm = last[gid] - mv[e];
  out[gid] = gamma[e] * xm / sqrtf(mv[EE + e] + 1e-5f) + beta[e];
}

// ---------------- launcher ----------------
extern "C" void kernel_launch(void* const* d_in, const int* in_sizes, int n_in,
                              void* d_out, int out_size, void* d_ws, size_t ws_size,
                              hipStream_t stream)
{
  (void)in_sizes; (void)n_in; (void)out_size;
  const float* x     = (const float*)d_in[0];
  const int*   lens  = (const int*)d_in[1];
  const float* Wih_c = (const float*)d_in[3];
  const float* Whh_c = (const float*)d_in[4];
  const float* bih_c = (const float*)d_in[5];
  const float* bhh_c = (const float*)d_in[6];
  const float* Wmu   = (const float*)d_in[7];
  const float* bmu   = (const float*)d_in[8];
  const float* Wlv   = (const float*)d_in[9];
  const float* blv   = (const float*)d_in[10];
  const float* Wih_r = (const float*)d_in[11];
  const float* Whh_r = (const float*)d_in[12];
  const float* bih_r = (const float*)d_in[13];
  const float* bhh_r = (const float*)d_in[14];
  const float* gam   = (const float*)d_in[15];
  const float* bet   = (const float*)d_in[16];
  float* out = (float*)d_out;

  // jax.random.split(key(42), 4), partitionable/foldlike: nk[i] = threefry((0,42), 0, i)
  uint32_t nk[4][2];
  for (uint32_t i = 0; i < 4; ++i) tf2x32(0u, 42u, 0u, i, &nk[i][0], &nk[i][1]);

  float* ws = (float*)d_ws;
  size_t off = 0;
  float* U      = ws + off; off += 16384000;   // gi_all (stage-1) then mu_all (aliased)
  float* hx_all = ws + off; off += 4915200;
  float* lv_all = ws + off; off += 32768;
  float* texts  = ws + off; off += 4915200;
  float* hx0    = ws + off; off += 38400;
  float* h2     = ws + off; off += 131072;
  float* parts  = ws + off; off += 3145728;
  float* lastb  = ws + off; off += 131072;
  float* mv     = ws + off; off += 2048;
  if (ws_size < off * sizeof(float)) return;   // workspace too small: fail visibly

  hipMemsetAsync(hx0, 0, 38400 * sizeof(float), stream);
  hipMemsetAsync(h2,  0, 131072 * sizeof(float), stream);

  // stage-1 input projection (all timesteps, batched)
  k_gemm_gi<<<dim3(15, 256), 256, 0, stream>>>(x, Wih_c, bih_c, U);
  // stage-1 recurrence
  for (int t = 0; t < TT; ++t){
    const float* hp = (t == 0) ? hx0 : (hx_all + (long)(t - 1) * BB * DD);
    k_hx_step<<<dim3(38, 2), 256, 0, stream>>>(t, hp, Whh_c, bhh_c, U,
                                               hx_all + (long)t * BB * DD);
  }
  // batched mu / lv / sampling (overwrites U as mu_all)
  k_gemm_mu<<<dim3(16, 256), 256, 0, stream>>>(x, hx_all, Wmu, bmu, U);
  k_lv<<<dim3(64), 256, 0, stream>>>(x, hx_all, Wlv, blv, lv_all);
  k_sample<<<dim3(16384), 256, 0, stream>>>(x, U, lv_all, texts, out,
      nk[0][0], nk[0][1], nk[1][0], nk[1][1],
      nk[2][0], nk[2][1], nk[3][0], nk[3][1]);
  // stage-2 recurrence
  for (int t = 0; t < TT; ++t){
    k_gemm2<<<dim3(48, 4, 4), 256, 0, stream>>>(t, h2, texts, Whh_r, Wih_r, parts);
    k_gate2<<<dim3(512), 256, 0, stream>>>(t, parts, bih_r, bhh_r, lens, h2, lastb);
  }
  // batchnorm
  k_bn_stats<<<dim3(4), 256, 0, stream>>>(lastb, mv);
  k_bn_apply<<<dim3(512), 256, 0, stream>>>(lastb, mv, gam, bet, out);
}